// Round 12
// baseline (297.379 us; speedup 1.0000x reference)
//
#include <hip/hip_runtime.h>
#include <hip/hip_fp16.h>

// ---------------------------------------------------------------------------
// 3-layer GCN + linear head.  N=50000 nodes, E=800000 edges, D=128.
// CSR stores FULL norm value (q15 of w*dinv_s*dinv_d) so GEMMs are pure
// h@W -> GEMM1 is graph-independent and FUSED (block-split) into the atomic
// edge-count pass. Build: padded u64 atomic (count<<32 | q15-wsum, 1/64B
// line) -> scan_a -> scan_c (self-derives block offset; scan_b merged) ->
// fill.  Agg: wave-per-node, 32-slot bounds-predicated iteration
// (8 gathers/lane in flight; mean degree 16 -> single iteration).
// 11 dispatches total.
// ---------------------------------------------------------------------------

#define D 128
#define CNT64_STRIDE 8    // one u64 counter per 64 B cache line

typedef __attribute__((ext_vector_type(8))) _Float16 half8;
typedef __attribute__((ext_vector_type(4))) float floatx4;

// ---- MFMA GEMM body: C = A @ W (+bias), fp16 in/out, fp32 accum ----------
// 128 rows/block (4 waves x 32 rows), v_mfma_f32_16x16x32_f16.
// W (fp32) staged transposed as fp16 in LDS (Wl[n][k], pad->136).
// Layouts (m89/m91): A[m=lane&15][k=quad*8+j], B[k=quad*8+j][n=lane&15],
// C/D col=lane&15, row=quad*4+reg.
template <bool A_IS_F32>
__device__ __forceinline__ void gemm_body(int bid, const void* Aptr,
                                          const float* W, const float* bias,
                                          float* C32, __half* C16, int N) {
    __shared__ _Float16 Wl[128][136];
    int tid = threadIdx.x;

#pragma unroll
    for (int j = 0; j < 64; j++) {
        int e = tid + j * 256;          // 16384 elements
        int k = e >> 7, n = e & 127;
        Wl[n][k] = (_Float16)W[e];
    }
    __syncthreads();

    int wave = tid >> 6, lane = tid & 63;
    int m = lane & 15, q = lane >> 4;
    int R0 = bid * 128 + wave * 32;   // row tiles R0, R0+16

    const float*  A32p = (const float*)Aptr;
    const __half* A16p = (const __half*)Aptr;

    floatx4 acc[2][8];
#pragma unroll
    for (int rt = 0; rt < 2; rt++)
#pragma unroll
        for (int ct = 0; ct < 8; ct++) acc[rt][ct] = (floatx4){0.f, 0.f, 0.f, 0.f};

#pragma unroll
    for (int kk = 0; kk < 4; kk++) {
        half8 a[2];
#pragma unroll
        for (int rt = 0; rt < 2; rt++) {
            int row = R0 + rt * 16 + m;
            half8 t = {0, 0, 0, 0, 0, 0, 0, 0};
            if (row < N) {
                if (A_IS_F32) {
                    const float* p = &A32p[(size_t)row * 128 + kk * 32 + q * 8];
                    float4 f0 = *(const float4*)p;
                    float4 f1 = *(const float4*)(p + 4);
                    t[0] = (_Float16)f0.x; t[1] = (_Float16)f0.y;
                    t[2] = (_Float16)f0.z; t[3] = (_Float16)f0.w;
                    t[4] = (_Float16)f1.x; t[5] = (_Float16)f1.y;
                    t[6] = (_Float16)f1.z; t[7] = (_Float16)f1.w;
                } else {
                    t = *(const half8*)&A16p[(size_t)row * 128 + kk * 32 + q * 8];
                }
            }
            a[rt] = t;
        }
#pragma unroll
        for (int ct = 0; ct < 8; ct++) {
            half8 b = *(const half8*)&Wl[ct * 16 + m][kk * 32 + q * 8];
            acc[0][ct] = __builtin_amdgcn_mfma_f32_16x16x32_f16(a[0], b, acc[0][ct], 0, 0, 0);
            acc[1][ct] = __builtin_amdgcn_mfma_f32_16x16x32_f16(a[1], b, acc[1][ct], 0, 0, 0);
        }
    }

#pragma unroll
    for (int rt = 0; rt < 2; rt++) {
#pragma unroll
        for (int r = 0; r < 4; r++) {
            int row = R0 + rt * 16 + q * 4 + r;
            if (row >= N) continue;
#pragma unroll
            for (int ct = 0; ct < 8; ct++) {
                int col = ct * 16 + m;
                float v = acc[rt][ct][r];
                if (C16) C16[(size_t)row * 128 + col] = __float2half_rn(v);
                if (C32) C32[(size_t)row * 128 + col] = v + bias[col];
            }
        }
    }
}

template <bool A_IS_F32>
__global__ __launch_bounds__(256) void k_gemm_mfma(const void* __restrict__ Aptr,
                                                   const float* __restrict__ W,
                                                   const float* __restrict__ bias,
                                                   float* __restrict__ C32,
                                                   __half* __restrict__ C16, int N) {
    gemm_body<A_IS_F32>(blockIdx.x, Aptr, W, bias, C32, C16, N);
}

// ---- fused: blocks [0,gg) = GEMM1 (x@W1 -> y16); [gg,..) = edge atomics ---
__global__ __launch_bounds__(256) void k_build_gemm1(const float* __restrict__ x,
                                                     const float* __restrict__ W1,
                                                     __half* __restrict__ y16,
                                                     const int* __restrict__ dst,
                                                     const float* __restrict__ w,
                                                     unsigned long long* __restrict__ cnt8,
                                                     int* __restrict__ loc,
                                                     int N, int E, int gg) {
    if ((int)blockIdx.x < gg) {
        gemm_body<true>(blockIdx.x, x, W1, nullptr, nullptr, y16, N);
        return;
    }
    int e = ((int)blockIdx.x - gg) * 256 + threadIdx.x;
    if (e < E) {
        int d = dst[e];
        unsigned int wq = __float2uint_rn(w[e] * 32767.0f);
        unsigned long long old =
            atomicAdd(&cnt8[(size_t)d * CNT64_STRIDE], (1ull << 32) | (unsigned long long)wq);
        loc[e] = (int)(old >> 32);
    }
}

// ---- block-wide exclusive scan helper (256 threads) -----------------------
__device__ inline int block_exscan_256(int v) {
    int tid = threadIdx.x;
    int lane = tid & 63, wv = tid >> 6;
    int incl = v;
#pragma unroll
    for (int d = 1; d < 64; d <<= 1) {
        int n = __shfl_up(incl, d, 64);
        if (lane >= d) incl += n;
    }
    __shared__ int wsum[4];
    if (lane == 63) wsum[wv] = incl;
    __syncthreads();
    int woff = 0;
#pragma unroll
    for (int j = 0; j < 4; j++) woff += (j < wv) ? wsum[j] : 0;
    return woff + incl - v;
}

__global__ __launch_bounds__(256) void k_scan_a(const unsigned long long* __restrict__ cnt8,
                                                int* bsum, int N) {
    int i = blockIdx.x * 256 + threadIdx.x;
    int v = (i < N) ? (int)(cnt8[(size_t)i * CNT64_STRIDE] >> 32) : 0;
#pragma unroll
    for (int d = 32; d; d >>= 1) v += __shfl_down(v, d, 64);
    __shared__ int ws4[4];
    int lane = threadIdx.x & 63, wv = threadIdx.x >> 6;
    if (lane == 0) ws4[wv] = v;
    __syncthreads();
    if (threadIdx.x == 0) bsum[blockIdx.x] = ws4[0] + ws4[1] + ws4[2] + ws4[3];
}

// ---- scan_c (scan_b merged): each block derives its own offset by summing
// bsum[0..bid-1] (L2-hot, <=256 ints); also emits dinv from packed counters.
__global__ __launch_bounds__(256) void k_scan_c(const unsigned long long* __restrict__ cnt8,
                                                const int* __restrict__ bsum,
                                                int* rp, float* dinv, int N, int E) {
    int tid = threadIdx.x;
    int bid = blockIdx.x;

    // block offset = sum of previous blocks' counts
    int vb = (tid < bid) ? bsum[tid] : 0;   // bid <= 195 < 256
#pragma unroll
    for (int d = 32; d; d >>= 1) vb += __shfl_down(vb, d, 64);
    __shared__ int s4[4];
    int lane = tid & 63, wv = tid >> 6;
    if (lane == 0) s4[wv] = vb;
    __syncthreads();
    int boffv = s4[0] + s4[1] + s4[2] + s4[3];
    __syncthreads();   // s4 reuse barrier (exscan uses its own array)

    int i = bid * 256 + tid;
    unsigned long long p = (i < N) ? cnt8[(size_t)i * CNT64_STRIDE] : 0ull;
    int v = (int)(p >> 32);
    int ex = block_exscan_256(v);
    if (i < N) {
        rp[i] = boffv + ex;
        dinv[i] = rsqrtf(1.0f + (float)(unsigned int)p * (1.0f / 32767.0f));
    }
    if (i == 0) rp[N] = E;
}

// ---- CSR fill: ev[p] = (q15(w*dinv_s*dinv_d) << 17) | src -----------------
__global__ __launch_bounds__(256) void k_fill(const int* __restrict__ ei,
                                              const float* __restrict__ w,
                                              const float* __restrict__ dinv,
                                              const int* __restrict__ rp,
                                              const int* __restrict__ loc,
                                              unsigned int* __restrict__ ev, int E) {
    int e = blockIdx.x * 256 + threadIdx.x;
    if (e < E) {
        int s = ei[e];
        int d = ei[E + e];
        int p = rp[d] + loc[e];
        float val = w[e] * dinv[s] * dinv[d];   // in [0,1)
        unsigned int wq = __float2uint_rn(val * 32767.0f);
        ev[p] = (wq << 17) | (unsigned int)s;
    }
}

// ---- aggregation: out_i = b + dinv_i^2*y_i + sum val*y_src ---------------
// One wave per node; quarter-wave (16 lanes) per edge slot; lane sl=lane&15
// covers features sl*8..sl*8+7 as one uint4 (8 fp16). 32-slot predicated
// iteration: 8 gathers/lane in flight; mean degree 16 and P(deg>32)~3e-5 so
// virtually all nodes take one iteration (loop kept for correctness).
__global__ __launch_bounds__(256) void k_agg(const __half* __restrict__ y16,
                                             const int* __restrict__ rp,
                                             const unsigned int* __restrict__ ev,
                                             const float* __restrict__ dinv,
                                             const float* __restrict__ bias,
                                             __half* __restrict__ out16,
                                             int N, int relu) {
    int i = blockIdx.x * 4 + (threadIdx.x >> 6);
    if (i >= N) return;
    int lane = threadIdx.x & 63;
    int g = lane >> 4;
    int sl = lane & 15;

    float acc[8];
#pragma unroll
    for (int j = 0; j < 8; j++) acc[j] = 0.f;

    int e0 = rp[i], e1 = rp[i + 1];

    for (int e = e0; e < e1; e += 32) {
        unsigned int p[8];
        float v[8];
        uint4 q[8];
#pragma unroll
        for (int u = 0; u < 8; u++) {
            int idx = e + u * 4 + g;
            bool ok = idx < e1;
            p[u] = ev[ok ? idx : e0];
            v[u] = ok ? (float)(p[u] >> 17) * (1.0f / 32767.0f) : 0.0f;
        }
#pragma unroll
        for (int u = 0; u < 8; u++)
            q[u] = *(const uint4*)&y16[(size_t)(p[u] & 0x1FFFFu) * D + sl * 8];
#pragma unroll
        for (int u = 0; u < 8; u++) {
            union { uint4 uu; __half2 h2[4]; } U; U.uu = q[u];
            float2 f0 = __half22float2(U.h2[0]);
            float2 f1 = __half22float2(U.h2[1]);
            float2 f2 = __half22float2(U.h2[2]);
            float2 f3 = __half22float2(U.h2[3]);
            acc[0] = fmaf(v[u], f0.x, acc[0]); acc[1] = fmaf(v[u], f0.y, acc[1]);
            acc[2] = fmaf(v[u], f1.x, acc[2]); acc[3] = fmaf(v[u], f1.y, acc[3]);
            acc[4] = fmaf(v[u], f2.x, acc[4]); acc[5] = fmaf(v[u], f2.y, acc[5]);
            acc[6] = fmaf(v[u], f3.x, acc[6]); acc[7] = fmaf(v[u], f3.y, acc[7]);
        }
    }

    // fold the 4 quarter-wave partials (lane ^16, ^32)
#pragma unroll
    for (int j = 0; j < 8; j++) {
        acc[j] += __shfl_xor(acc[j], 16, 64);
        acc[j] += __shfl_xor(acc[j], 32, 64);
    }

    if (g == 0) {
        float di = dinv[i];
        float di2 = di * di;
        union { uint4 u; __half2 h2[4]; } S;
        S.u = *(const uint4*)&y16[(size_t)i * D + sl * 8];
        float2 s0 = __half22float2(S.h2[0]);
        float2 s1 = __half22float2(S.h2[1]);
        float2 s2 = __half22float2(S.h2[2]);
        float2 s3 = __half22float2(S.h2[3]);
        float4 b0 = *(const float4*)&bias[sl * 8];
        float4 b1 = *(const float4*)&bias[sl * 8 + 4];
        float o[8];
        o[0] = b0.x + acc[0] + di2 * s0.x;
        o[1] = b0.y + acc[1] + di2 * s0.y;
        o[2] = b0.z + acc[2] + di2 * s1.x;
        o[3] = b0.w + acc[3] + di2 * s1.y;
        o[4] = b1.x + acc[4] + di2 * s2.x;
        o[5] = b1.y + acc[5] + di2 * s2.y;
        o[6] = b1.z + acc[6] + di2 * s3.x;
        o[7] = b1.w + acc[7] + di2 * s3.y;
        if (relu) {
#pragma unroll
            for (int j = 0; j < 8; j++) o[j] = fmaxf(o[j], 0.f);
        }
        union { uint4 u; __half2 h2[4]; } O;
        O.h2[0] = __float22half2_rn(make_float2(o[0], o[1]));
        O.h2[1] = __float22half2_rn(make_float2(o[2], o[3]));
        O.h2[2] = __float22half2_rn(make_float2(o[4], o[5]));
        O.h2[3] = __float22half2_rn(make_float2(o[6], o[7]));
        *(uint4*)&out16[(size_t)i * D + sl * 8] = O.u;
    }
}

// ---------------------------------------------------------------------------
extern "C" void kernel_launch(void* const* d_in, const int* in_sizes, int n_in,
                              void* d_out, int out_size, void* d_ws, size_t ws_size,
                              hipStream_t stream) {
    const float* x  = (const float*)d_in[0];
    const int*   ei = (const int*)d_in[1];     // [2,E]: src row then dst row
    const float* ew = (const float*)d_in[2];
    const float* W1 = (const float*)d_in[3];
    const float* b1 = (const float*)d_in[4];
    const float* W2 = (const float*)d_in[5];
    const float* b2 = (const float*)d_in[6];
    const float* W3 = (const float*)d_in[7];
    const float* b3 = (const float*)d_in[8];
    const float* Wl = (const float*)d_in[9];
    const float* bl = (const float*)d_in[10];

    int N = in_sizes[0] / D;    // 50000
    int E = in_sizes[2];        // 800000

    char* ws = (char*)d_ws;
    size_t off = 0;
    auto alloc = [&](size_t bytes) {
        void* p = ws + off;
        off = (off + bytes + 255) & ~(size_t)255;
        return p;
    };
    unsigned long long* cnt8 = (unsigned long long*)alloc((size_t)N * 64); // padded
    float*  dinv = (float*)alloc((size_t)N * 4);
    int*    bsum = (int*)  alloc(1024);
    int*    rp   = (int*)  alloc((size_t)(N + 1) * 4);
    int*    loc  = (int*)  alloc((size_t)E * 4);
    unsigned int* ev = (unsigned int*)alloc((size_t)E * 4);
    __half* y16  = (__half*)alloc((size_t)N * D * 2);
    __half* z16  = (__half*)alloc((size_t)N * D * 2);

    int nbN = (N + 255) / 256;      // 196 (<= 256 for scan offset derivation)
    int nbE = (E + 255) / 256;      // 3125
    int gg  = (N + 127) / 128;      // 391 GEMM blocks
    int ga  = (N + 3) / 4;          // agg blocks (4 waves each)

    hipMemsetAsync(cnt8, 0, (size_t)N * 64, stream);
    // fused: GEMM1 (graph-independent) + edge-count atomics in one dispatch
    k_build_gemm1<<<gg + nbE, 256, 0, stream>>>(x, W1, y16, ei + E, ew,
                                                cnt8, loc, N, E, gg);
    k_scan_a<<<nbN, 256, 0, stream>>>(cnt8, bsum, N);
    k_scan_c<<<nbN, 256, 0, stream>>>(cnt8, bsum, rp, dinv, N, E);
    k_fill<<<nbE, 256, 0, stream>>>(ei, ew, dinv, rp, loc, ev, E);

    k_agg<<<ga, 256, 0, stream>>>(y16, rp, ev, dinv, b1, z16, N, 1);
    k_gemm_mfma<false><<<gg, 256, 0, stream>>>(z16, W2, nullptr, nullptr, y16, N);
    k_agg<<<ga, 256, 0, stream>>>(y16, rp, ev, dinv, b2, z16, N, 1);
    k_gemm_mfma<false><<<gg, 256, 0, stream>>>(z16, W3, nullptr, nullptr, y16, N);
    k_agg<<<ga, 256, 0, stream>>>(y16, rp, ev, dinv, b3, z16, N, 0);
    k_gemm_mfma<false><<<gg, 256, 0, stream>>>(z16, Wl, bl, (float*)d_out, nullptr, N);
}

// Round 13
// 283.650 us; speedup vs baseline: 1.0484x; 1.0484x over previous
//
#include <hip/hip_runtime.h>
#include <hip/hip_fp16.h>

// ---------------------------------------------------------------------------
// 3-layer GCN + linear head.  N=50000 nodes, E=800000 edges, D=128.
// CSR stores FULL norm value (q15 of w*dinv_s*dinv_d) so GEMMs are pure
// h@W -> GEMM1 is graph-independent and FUSED (block-split) into the atomic
// edge-count pass. Build: padded u64 atomic (count<<32 | q15-wsum, 1/64B
// line) -> scan_a -> scan_c (self-derives block offset; scan_b merged) ->
// fill.  Agg: wave-per-node, 16-slot bounds-predicated iteration (4 gathers
// per lane in flight; mean degree 16 -> ~1 iteration).
// [R12 lesson: widening to 32 slots costs VGPR/occupancy + redundant
//  predicated gathers on every node -> +12us. 16 is the sweet spot.]
// 11 dispatches total.
// ---------------------------------------------------------------------------

#define D 128
#define CNT64_STRIDE 8    // one u64 counter per 64 B cache line

typedef __attribute__((ext_vector_type(8))) _Float16 half8;
typedef __attribute__((ext_vector_type(4))) float floatx4;

// ---- MFMA GEMM body: C = A @ W (+bias), fp16 in/out, fp32 accum ----------
// 128 rows/block (4 waves x 32 rows), v_mfma_f32_16x16x32_f16.
// W (fp32) staged transposed as fp16 in LDS (Wl[n][k], pad->136).
// Layouts (m89/m91): A[m=lane&15][k=quad*8+j], B[k=quad*8+j][n=lane&15],
// C/D col=lane&15, row=quad*4+reg.
template <bool A_IS_F32>
__device__ __forceinline__ void gemm_body(int bid, const void* Aptr,
                                          const float* W, const float* bias,
                                          float* C32, __half* C16, int N) {
    __shared__ _Float16 Wl[128][136];
    int tid = threadIdx.x;

#pragma unroll
    for (int j = 0; j < 64; j++) {
        int e = tid + j * 256;          // 16384 elements
        int k = e >> 7, n = e & 127;
        Wl[n][k] = (_Float16)W[e];
    }
    __syncthreads();

    int wave = tid >> 6, lane = tid & 63;
    int m = lane & 15, q = lane >> 4;
    int R0 = bid * 128 + wave * 32;   // row tiles R0, R0+16

    const float*  A32p = (const float*)Aptr;
    const __half* A16p = (const __half*)Aptr;

    floatx4 acc[2][8];
#pragma unroll
    for (int rt = 0; rt < 2; rt++)
#pragma unroll
        for (int ct = 0; ct < 8; ct++) acc[rt][ct] = (floatx4){0.f, 0.f, 0.f, 0.f};

#pragma unroll
    for (int kk = 0; kk < 4; kk++) {
        half8 a[2];
#pragma unroll
        for (int rt = 0; rt < 2; rt++) {
            int row = R0 + rt * 16 + m;
            half8 t = {0, 0, 0, 0, 0, 0, 0, 0};
            if (row < N) {
                if (A_IS_F32) {
                    const float* p = &A32p[(size_t)row * 128 + kk * 32 + q * 8];
                    float4 f0 = *(const float4*)p;
                    float4 f1 = *(const float4*)(p + 4);
                    t[0] = (_Float16)f0.x; t[1] = (_Float16)f0.y;
                    t[2] = (_Float16)f0.z; t[3] = (_Float16)f0.w;
                    t[4] = (_Float16)f1.x; t[5] = (_Float16)f1.y;
                    t[6] = (_Float16)f1.z; t[7] = (_Float16)f1.w;
                } else {
                    t = *(const half8*)&A16p[(size_t)row * 128 + kk * 32 + q * 8];
                }
            }
            a[rt] = t;
        }
#pragma unroll
        for (int ct = 0; ct < 8; ct++) {
            half8 b = *(const half8*)&Wl[ct * 16 + m][kk * 32 + q * 8];
            acc[0][ct] = __builtin_amdgcn_mfma_f32_16x16x32_f16(a[0], b, acc[0][ct], 0, 0, 0);
            acc[1][ct] = __builtin_amdgcn_mfma_f32_16x16x32_f16(a[1], b, acc[1][ct], 0, 0, 0);
        }
    }

#pragma unroll
    for (int rt = 0; rt < 2; rt++) {
#pragma unroll
        for (int r = 0; r < 4; r++) {
            int row = R0 + rt * 16 + q * 4 + r;
            if (row >= N) continue;
#pragma unroll
            for (int ct = 0; ct < 8; ct++) {
                int col = ct * 16 + m;
                float v = acc[rt][ct][r];
                if (C16) C16[(size_t)row * 128 + col] = __float2half_rn(v);
                if (C32) C32[(size_t)row * 128 + col] = v + bias[col];
            }
        }
    }
}

template <bool A_IS_F32>
__global__ __launch_bounds__(256) void k_gemm_mfma(const void* __restrict__ Aptr,
                                                   const float* __restrict__ W,
                                                   const float* __restrict__ bias,
                                                   float* __restrict__ C32,
                                                   __half* __restrict__ C16, int N) {
    gemm_body<A_IS_F32>(blockIdx.x, Aptr, W, bias, C32, C16, N);
}

// ---- fused: blocks [0,gg) = GEMM1 (x@W1 -> y16); [gg,..) = edge atomics ---
__global__ __launch_bounds__(256) void k_build_gemm1(const float* __restrict__ x,
                                                     const float* __restrict__ W1,
                                                     __half* __restrict__ y16,
                                                     const int* __restrict__ dst,
                                                     const float* __restrict__ w,
                                                     unsigned long long* __restrict__ cnt8,
                                                     int* __restrict__ loc,
                                                     int N, int E, int gg) {
    if ((int)blockIdx.x < gg) {
        gemm_body<true>(blockIdx.x, x, W1, nullptr, nullptr, y16, N);
        return;
    }
    int e = ((int)blockIdx.x - gg) * 256 + threadIdx.x;
    if (e < E) {
        int d = dst[e];
        unsigned int wq = __float2uint_rn(w[e] * 32767.0f);
        unsigned long long old =
            atomicAdd(&cnt8[(size_t)d * CNT64_STRIDE], (1ull << 32) | (unsigned long long)wq);
        loc[e] = (int)(old >> 32);
    }
}

// ---- block-wide exclusive scan helper (256 threads) -----------------------
__device__ inline int block_exscan_256(int v) {
    int tid = threadIdx.x;
    int lane = tid & 63, wv = tid >> 6;
    int incl = v;
#pragma unroll
    for (int d = 1; d < 64; d <<= 1) {
        int n = __shfl_up(incl, d, 64);
        if (lane >= d) incl += n;
    }
    __shared__ int wsum[4];
    if (lane == 63) wsum[wv] = incl;
    __syncthreads();
    int woff = 0;
#pragma unroll
    for (int j = 0; j < 4; j++) woff += (j < wv) ? wsum[j] : 0;
    return woff + incl - v;
}

__global__ __launch_bounds__(256) void k_scan_a(const unsigned long long* __restrict__ cnt8,
                                                int* bsum, int N) {
    int i = blockIdx.x * 256 + threadIdx.x;
    int v = (i < N) ? (int)(cnt8[(size_t)i * CNT64_STRIDE] >> 32) : 0;
#pragma unroll
    for (int d = 32; d; d >>= 1) v += __shfl_down(v, d, 64);
    __shared__ int ws4[4];
    int lane = threadIdx.x & 63, wv = threadIdx.x >> 6;
    if (lane == 0) ws4[wv] = v;
    __syncthreads();
    if (threadIdx.x == 0) bsum[blockIdx.x] = ws4[0] + ws4[1] + ws4[2] + ws4[3];
}

// ---- scan_c (scan_b merged): each block derives its own offset by summing
// bsum[0..bid-1] (L2-hot, <=256 ints); also emits dinv from packed counters.
__global__ __launch_bounds__(256) void k_scan_c(const unsigned long long* __restrict__ cnt8,
                                                const int* __restrict__ bsum,
                                                int* rp, float* dinv, int N, int E) {
    int tid = threadIdx.x;
    int bid = blockIdx.x;

    // block offset = sum of previous blocks' counts
    int vb = (tid < bid) ? bsum[tid] : 0;   // bid <= 195 < 256
#pragma unroll
    for (int d = 32; d; d >>= 1) vb += __shfl_down(vb, d, 64);
    __shared__ int s4[4];
    int lane = tid & 63, wv = tid >> 6;
    if (lane == 0) s4[wv] = vb;
    __syncthreads();
    int boffv = s4[0] + s4[1] + s4[2] + s4[3];
    __syncthreads();   // s4 reuse barrier (exscan uses its own array)

    int i = bid * 256 + tid;
    unsigned long long p = (i < N) ? cnt8[(size_t)i * CNT64_STRIDE] : 0ull;
    int v = (int)(p >> 32);
    int ex = block_exscan_256(v);
    if (i < N) {
        rp[i] = boffv + ex;
        dinv[i] = rsqrtf(1.0f + (float)(unsigned int)p * (1.0f / 32767.0f));
    }
    if (i == 0) rp[N] = E;
}

// ---- CSR fill: ev[p] = (q15(w*dinv_s*dinv_d) << 17) | src -----------------
__global__ __launch_bounds__(256) void k_fill(const int* __restrict__ ei,
                                              const float* __restrict__ w,
                                              const float* __restrict__ dinv,
                                              const int* __restrict__ rp,
                                              const int* __restrict__ loc,
                                              unsigned int* __restrict__ ev, int E) {
    int e = blockIdx.x * 256 + threadIdx.x;
    if (e < E) {
        int s = ei[e];
        int d = ei[E + e];
        int p = rp[d] + loc[e];
        float val = w[e] * dinv[s] * dinv[d];   // in [0,1)
        unsigned int wq = __float2uint_rn(val * 32767.0f);
        ev[p] = (wq << 17) | (unsigned int)s;
    }
}

// ---- aggregation: out_i = b + dinv_i^2*y_i + sum val*y_src ---------------
// One wave per node; quarter-wave (16 lanes) per edge slot; lane sl=lane&15
// covers features sl*8..sl*8+7 as one uint4 (8 fp16). 16-slot bounds-
// predicated iteration: 4 gathers/lane in flight regardless of degree
// (invalid slots clamp to e0, weight 0).
__global__ __launch_bounds__(256) void k_agg(const __half* __restrict__ y16,
                                             const int* __restrict__ rp,
                                             const unsigned int* __restrict__ ev,
                                             const float* __restrict__ dinv,
                                             const float* __restrict__ bias,
                                             __half* __restrict__ out16,
                                             int N, int relu) {
    int i = blockIdx.x * 4 + (threadIdx.x >> 6);
    if (i >= N) return;
    int lane = threadIdx.x & 63;
    int g = lane >> 4;
    int sl = lane & 15;

    float acc[8];
#pragma unroll
    for (int j = 0; j < 8; j++) acc[j] = 0.f;

    int e0 = rp[i], e1 = rp[i + 1];

    for (int e = e0; e < e1; e += 16) {
        unsigned int p[4];
        float v[4];
        uint4 q[4];
#pragma unroll
        for (int u = 0; u < 4; u++) {
            int idx = e + u * 4 + g;
            bool ok = idx < e1;
            p[u] = ev[ok ? idx : e0];
            v[u] = ok ? (float)(p[u] >> 17) * (1.0f / 32767.0f) : 0.0f;
        }
#pragma unroll
        for (int u = 0; u < 4; u++)
            q[u] = *(const uint4*)&y16[(size_t)(p[u] & 0x1FFFFu) * D + sl * 8];
#pragma unroll
        for (int u = 0; u < 4; u++) {
            union { uint4 uu; __half2 h2[4]; } U; U.uu = q[u];
            float2 f0 = __half22float2(U.h2[0]);
            float2 f1 = __half22float2(U.h2[1]);
            float2 f2 = __half22float2(U.h2[2]);
            float2 f3 = __half22float2(U.h2[3]);
            acc[0] = fmaf(v[u], f0.x, acc[0]); acc[1] = fmaf(v[u], f0.y, acc[1]);
            acc[2] = fmaf(v[u], f1.x, acc[2]); acc[3] = fmaf(v[u], f1.y, acc[3]);
            acc[4] = fmaf(v[u], f2.x, acc[4]); acc[5] = fmaf(v[u], f2.y, acc[5]);
            acc[6] = fmaf(v[u], f3.x, acc[6]); acc[7] = fmaf(v[u], f3.y, acc[7]);
        }
    }

    // fold the 4 quarter-wave partials (lane ^16, ^32)
#pragma unroll
    for (int j = 0; j < 8; j++) {
        acc[j] += __shfl_xor(acc[j], 16, 64);
        acc[j] += __shfl_xor(acc[j], 32, 64);
    }

    if (g == 0) {
        float di = dinv[i];
        float di2 = di * di;
        union { uint4 u; __half2 h2[4]; } S;
        S.u = *(const uint4*)&y16[(size_t)i * D + sl * 8];
        float2 s0 = __half22float2(S.h2[0]);
        float2 s1 = __half22float2(S.h2[1]);
        float2 s2 = __half22float2(S.h2[2]);
        float2 s3 = __half22float2(S.h2[3]);
        float4 b0 = *(const float4*)&bias[sl * 8];
        float4 b1 = *(const float4*)&bias[sl * 8 + 4];
        float o[8];
        o[0] = b0.x + acc[0] + di2 * s0.x;
        o[1] = b0.y + acc[1] + di2 * s0.y;
        o[2] = b0.z + acc[2] + di2 * s1.x;
        o[3] = b0.w + acc[3] + di2 * s1.y;
        o[4] = b1.x + acc[4] + di2 * s2.x;
        o[5] = b1.y + acc[5] + di2 * s2.y;
        o[6] = b1.z + acc[6] + di2 * s3.x;
        o[7] = b1.w + acc[7] + di2 * s3.y;
        if (relu) {
#pragma unroll
            for (int j = 0; j < 8; j++) o[j] = fmaxf(o[j], 0.f);
        }
        union { uint4 u; __half2 h2[4]; } O;
        O.h2[0] = __float22half2_rn(make_float2(o[0], o[1]));
        O.h2[1] = __float22half2_rn(make_float2(o[2], o[3]));
        O.h2[2] = __float22half2_rn(make_float2(o[4], o[5]));
        O.h2[3] = __float22half2_rn(make_float2(o[6], o[7]));
        *(uint4*)&out16[(size_t)i * D + sl * 8] = O.u;
    }
}

// ---------------------------------------------------------------------------
extern "C" void kernel_launch(void* const* d_in, const int* in_sizes, int n_in,
                              void* d_out, int out_size, void* d_ws, size_t ws_size,
                              hipStream_t stream) {
    const float* x  = (const float*)d_in[0];
    const int*   ei = (const int*)d_in[1];     // [2,E]: src row then dst row
    const float* ew = (const float*)d_in[2];
    const float* W1 = (const float*)d_in[3];
    const float* b1 = (const float*)d_in[4];
    const float* W2 = (const float*)d_in[5];
    const float* b2 = (const float*)d_in[6];
    const float* W3 = (const float*)d_in[7];
    const float* b3 = (const float*)d_in[8];
    const float* Wl = (const float*)d_in[9];
    const float* bl = (const float*)d_in[10];

    int N = in_sizes[0] / D;    // 50000
    int E = in_sizes[2];        // 800000

    char* ws = (char*)d_ws;
    size_t off = 0;
    auto alloc = [&](size_t bytes) {
        void* p = ws + off;
        off = (off + bytes + 255) & ~(size_t)255;
        return p;
    };
    unsigned long long* cnt8 = (unsigned long long*)alloc((size_t)N * 64); // padded
    float*  dinv = (float*)alloc((size_t)N * 4);
    int*    bsum = (int*)  alloc(1024);
    int*    rp   = (int*)  alloc((size_t)(N + 1) * 4);
    int*    loc  = (int*)  alloc((size_t)E * 4);
    unsigned int* ev = (unsigned int*)alloc((size_t)E * 4);
    __half* y16  = (__half*)alloc((size_t)N * D * 2);
    __half* z16  = (__half*)alloc((size_t)N * D * 2);

    int nbN = (N + 255) / 256;      // 196 (<= 256 for scan offset derivation)
    int nbE = (E + 255) / 256;      // 3125
    int gg  = (N + 127) / 128;      // 391 GEMM blocks
    int ga  = (N + 3) / 4;          // agg blocks (4 waves each)

    hipMemsetAsync(cnt8, 0, (size_t)N * 64, stream);
    // fused: GEMM1 (graph-independent) + edge-count atomics in one dispatch
    k_build_gemm1<<<gg + nbE, 256, 0, stream>>>(x, W1, y16, ei + E, ew,
                                                cnt8, loc, N, E, gg);
    k_scan_a<<<nbN, 256, 0, stream>>>(cnt8, bsum, N);
    k_scan_c<<<nbN, 256, 0, stream>>>(cnt8, bsum, rp, dinv, N, E);
    k_fill<<<nbE, 256, 0, stream>>>(ei, ew, dinv, rp, loc, ev, E);

    k_agg<<<ga, 256, 0, stream>>>(y16, rp, ev, dinv, b1, z16, N, 1);
    k_gemm_mfma<false><<<gg, 256, 0, stream>>>(z16, W2, nullptr, nullptr, y16, N);
    k_agg<<<ga, 256, 0, stream>>>(y16, rp, ev, dinv, b2, z16, N, 1);
    k_gemm_mfma<false><<<gg, 256, 0, stream>>>(z16, W3, nullptr, nullptr, y16, N);
    k_agg<<<ga, 256, 0, stream>>>(y16, rp, ev, dinv, b3, z16, N, 0);
    k_gemm_mfma<false><<<gg, 256, 0, stream>>>(z16, Wl, bl, (float*)d_out, nullptr, N);
}